// Round 1
// baseline (1085.242 us; speedup 1.0000x reference)
//
#include <hip/hip_runtime.h>

// Problem constants (fixed by the reference harness).
#define NNODES 100000
#define NEDGES 1600000
#define DIM    48
#define Q_PER_EDGE 12   // DIM/4 float4 chunks per edge
#define Q_PER_NODE 12

// ---------------------------------------------------------------------------
// Edge scatter: for each edge e, AY[dst[e]] += Y[src[e]] * w[e] * norm(src)^-0.5
// 12 threads per edge; each handles one float4 (4 features).
// ---------------------------------------------------------------------------
__global__ void edge_scatter_kernel(const float* __restrict__ Y,
                                    const float* __restrict__ w,
                                    const float* __restrict__ deg,
                                    const float* __restrict__ lam_p,
                                    const int*   __restrict__ src,
                                    const int*   __restrict__ dst,
                                    float* __restrict__ acc) {
    const long gid = (long)blockIdx.x * blockDim.x + threadIdx.x;
    if (gid >= (long)NEDGES * Q_PER_EDGE) return;
    const int e = (int)(gid / Q_PER_EDGE);
    const int q = (int)(gid % Q_PER_EDGE);

    const float lam = *lam_p;
    const int s = src[e];
    const int t = dst[e];
    // norm(src)^-0.5 computed on the fly (cheaper than a staging pass).
    const float scale = w[e] * rsqrtf(lam * deg[s] + (1.0f - lam));

    const float4 v = ((const float4*)(Y + (long)s * DIM))[q];
    float* out = acc + (long)t * DIM + q * 4;
    unsafeAtomicAdd(out + 0, v.x * scale);
    unsafeAtomicAdd(out + 1, v.y * scale);
    unsafeAtomicAdd(out + 2, v.z * scale);
    unsafeAtomicAdd(out + 3, v.w * scale);
}

// ---------------------------------------------------------------------------
// Finalize (in-place on acc == d_out, which currently holds AY):
//   out = (1-alp)*Y + alp*lam*AY*norm^-0.5 + alp*X*norm^-1
// float4-vectorized; one thread per 4 features.
// ---------------------------------------------------------------------------
__global__ void finalize_kernel(const float* __restrict__ Y,
                                const float* __restrict__ X,
                                const float* __restrict__ deg,
                                const float* __restrict__ alp_p,
                                const float* __restrict__ lam_p,
                                float* __restrict__ out) {
    const int gid = blockIdx.x * blockDim.x + threadIdx.x;
    if (gid >= NNODES * Q_PER_NODE) return;
    const int n = gid / Q_PER_NODE;

    const float alp = *alp_p;
    const float lam = *lam_p;
    const float ns = rsqrtf(lam * deg[n] + (1.0f - lam));  // norm^-0.5
    const float ni = ns * ns;                              // norm^-1

    const float4 y = ((const float4*)Y)[gid];
    const float4 x = ((const float4*)X)[gid];
    const float4 a = ((const float4*)out)[gid];

    const float c0 = 1.0f - alp;
    const float c1 = alp * lam * ns;
    const float c2 = alp * ni;

    float4 r;
    r.x = c0 * y.x + c1 * a.x + c2 * x.x;
    r.y = c0 * y.y + c1 * a.y + c2 * x.y;
    r.z = c0 * y.z + c1 * a.z + c2 * x.z;
    r.w = c0 * y.w + c1 * a.w + c2 * x.w;
    ((float4*)out)[gid] = r;
}

extern "C" void kernel_launch(void* const* d_in, const int* in_sizes, int n_in,
                              void* d_out, int out_size, void* d_ws, size_t ws_size,
                              hipStream_t stream) {
    const float* Y   = (const float*)d_in[0];
    const float* X   = (const float*)d_in[1];
    const float* w   = (const float*)d_in[2];
    const float* deg = (const float*)d_in[3];
    const float* alp = (const float*)d_in[4];
    const float* lam = (const float*)d_in[5];
    const int*   src = (const int*)d_in[6];
    const int*   dst = (const int*)d_in[7];
    float* out = (float*)d_out;

    // d_out is poisoned 0xAA before every call — zero it to serve as the
    // AY accumulator (graph-capture supports memset nodes).
    hipMemsetAsync(out, 0, sizeof(float) * NNODES * DIM, stream);

    const long edge_threads = (long)NEDGES * Q_PER_EDGE;   // 19.2M
    edge_scatter_kernel<<<(int)((edge_threads + 255) / 256), 256, 0, stream>>>(
        Y, w, deg, lam, src, dst, out);

    const int node_threads = NNODES * Q_PER_NODE;          // 1.2M
    finalize_kernel<<<(node_threads + 255) / 256, 256, 0, stream>>>(
        Y, X, deg, alp, lam, out);
}

// Round 2
// 313.788 us; speedup vs baseline: 3.4585x; 3.4585x over previous
//
#include <hip/hip_runtime.h>

// Problem constants (fixed by the reference harness).
#define NNODES 100000
#define NEDGES 1600000
#define DIM    48
#define QPN    12            // DIM/4 float4 chunks per node
#define SCAN_CHUNK 1024      // elements per scan_a block (256 thr x 4)
#define NBLK ((NNODES + SCAN_CHUNK - 1) / SCAN_CHUNK)   // 98

// Workspace layout (ints):
//   counts  [N]      @ 0
//   offs    [N]      @ N
//   cursor  [N]      @ 2N
//   bsums   [128]    @ 3N
//   boffs   [128]    @ 3N+128
//   csr     [E] u64  @ 3N+256  (byte offset 1201024, 8B aligned)
#define WS_COUNTS 0
#define WS_OFFS   (NNODES)
#define WS_CURSOR (2 * NNODES)
#define WS_BSUMS  (3 * NNODES)
#define WS_BOFFS  (3 * NNODES + 128)
#define WS_CSR    (3 * NNODES + 256)

// ---------------------------------------------------------------------------
// 1) In-degree histogram (counts must be pre-zeroed by memset).
// ---------------------------------------------------------------------------
__global__ void hist_kernel(const int* __restrict__ dst, int* __restrict__ counts) {
    const int e = blockIdx.x * blockDim.x + threadIdx.x;
    if (e < NEDGES) atomicAdd(&counts[dst[e]], 1);
}

// ---------------------------------------------------------------------------
// 2a) Per-chunk exclusive scan (256 thr x 4 elems), block totals to bsums.
// ---------------------------------------------------------------------------
__global__ void scan_a_kernel(const int* __restrict__ counts,
                              int* __restrict__ offs,
                              int* __restrict__ bsums) {
    const int b = blockIdx.x, t = threadIdx.x;
    const int base = b * SCAN_CHUNK + t * 4;
    const int v0 = (base + 0 < NNODES) ? counts[base + 0] : 0;
    const int v1 = (base + 1 < NNODES) ? counts[base + 1] : 0;
    const int v2 = (base + 2 < NNODES) ? counts[base + 2] : 0;
    const int v3 = (base + 3 < NNODES) ? counts[base + 3] : 0;
    const int s = v0 + v1 + v2 + v3;
    __shared__ int sh[256];
    sh[t] = s;
    __syncthreads();
    for (int off = 1; off < 256; off <<= 1) {
        const int x = (t >= off) ? sh[t - off] : 0;
        __syncthreads();
        sh[t] += x;
        __syncthreads();
    }
    const int excl = sh[t] - s;
    if (base + 0 < NNODES) offs[base + 0] = excl;
    if (base + 1 < NNODES) offs[base + 1] = excl + v0;
    if (base + 2 < NNODES) offs[base + 2] = excl + v0 + v1;
    if (base + 3 < NNODES) offs[base + 3] = excl + v0 + v1 + v2;
    if (t == 255) bsums[b] = sh[255];
}

// ---------------------------------------------------------------------------
// 2b) Scan of the 98 block totals (single block, 128 threads).
// ---------------------------------------------------------------------------
__global__ void scan_b_kernel(const int* __restrict__ bsums, int* __restrict__ boffs) {
    const int t = threadIdx.x;
    __shared__ int sh[128];
    const int v = (t < NBLK) ? bsums[t] : 0;
    sh[t] = v;
    __syncthreads();
    for (int off = 1; off < 128; off <<= 1) {
        const int x = (t >= off) ? sh[t - off] : 0;
        __syncthreads();
        sh[t] += x;
        __syncthreads();
    }
    if (t < NBLK) boffs[t] = sh[t] - v;
}

// ---------------------------------------------------------------------------
// 2c) Add block offsets; init cursor = final offsets.
// ---------------------------------------------------------------------------
__global__ void scan_c_kernel(int* __restrict__ offs,
                              const int* __restrict__ boffs,
                              int* __restrict__ cursor) {
    const int i = blockIdx.x * blockDim.x + threadIdx.x;
    if (i < NNODES) {
        const int o = offs[i] + boffs[i >> 10];
        offs[i] = o;
        cursor[i] = o;
    }
}

// ---------------------------------------------------------------------------
// 3) Fill CSR slots: payload = (scale bits << 32) | src. scale folds in
//    w[e] * norm(src)^-0.5 so the gather loop is a pure fma.
// ---------------------------------------------------------------------------
__global__ void fill_kernel(const int* __restrict__ src,
                            const int* __restrict__ dst,
                            const float* __restrict__ w,
                            const float* __restrict__ deg,
                            const float* __restrict__ lam_p,
                            int* __restrict__ cursor,
                            unsigned long long* __restrict__ csr) {
    const int e = blockIdx.x * blockDim.x + threadIdx.x;
    if (e >= NEDGES) return;
    const float lam = *lam_p;
    const int s = src[e];
    const float sc = w[e] * rsqrtf(lam * deg[s] + (1.0f - lam));
    const int slot = atomicAdd(&cursor[dst[e]], 1);
    csr[slot] = ((unsigned long long)__float_as_uint(sc) << 32) | (unsigned int)s;
}

// ---------------------------------------------------------------------------
// 4) Gather + fused finalize. 12 threads per node, one float4 each:
//    AY_q = sum_j Y[src_j][q] * scale_j ; out = (1-a)Y + a*lam*ns*AY + a*ni*X
// ---------------------------------------------------------------------------
__global__ void gather_kernel(const float* __restrict__ Y,
                              const float* __restrict__ X,
                              const float* __restrict__ deg,
                              const float* __restrict__ alp_p,
                              const float* __restrict__ lam_p,
                              const int* __restrict__ offs,
                              const int* __restrict__ counts,
                              const unsigned long long* __restrict__ csr,
                              float* __restrict__ out) {
    const int gid = blockIdx.x * blockDim.x + threadIdx.x;
    if (gid >= NNODES * QPN) return;
    const int n = gid / QPN;
    const int q = gid % QPN;

    const int st = offs[n];
    const int len = counts[n];

    float4 acc = make_float4(0.f, 0.f, 0.f, 0.f);
    for (int j = 0; j < len; ++j) {
        const unsigned long long p = csr[st + j];
        const int s = (int)(unsigned int)(p & 0xffffffffull);
        const float sc = __uint_as_float((unsigned int)(p >> 32));
        const float4 v = ((const float4*)(Y + (size_t)s * DIM))[q];
        acc.x += v.x * sc;
        acc.y += v.y * sc;
        acc.z += v.z * sc;
        acc.w += v.w * sc;
    }

    const float alp = *alp_p;
    const float lam = *lam_p;
    const float ns = rsqrtf(lam * deg[n] + (1.0f - lam));  // norm^-0.5
    const float ni = ns * ns;                              // norm^-1
    const float c0 = 1.0f - alp;
    const float c1 = alp * lam * ns;
    const float c2 = alp * ni;

    const float4 y = ((const float4*)Y)[gid];
    const float4 x = ((const float4*)X)[gid];
    float4 r;
    r.x = c0 * y.x + c1 * acc.x + c2 * x.x;
    r.y = c0 * y.y + c1 * acc.y + c2 * x.y;
    r.z = c0 * y.z + c1 * acc.z + c2 * x.z;
    r.w = c0 * y.w + c1 * acc.w + c2 * x.w;
    ((float4*)out)[gid] = r;
}

extern "C" void kernel_launch(void* const* d_in, const int* in_sizes, int n_in,
                              void* d_out, int out_size, void* d_ws, size_t ws_size,
                              hipStream_t stream) {
    const float* Y   = (const float*)d_in[0];
    const float* X   = (const float*)d_in[1];
    const float* w   = (const float*)d_in[2];
    const float* deg = (const float*)d_in[3];
    const float* alp = (const float*)d_in[4];
    const float* lam = (const float*)d_in[5];
    const int*   src = (const int*)d_in[6];
    const int*   dst = (const int*)d_in[7];
    float* out = (float*)d_out;

    int* ws = (int*)d_ws;
    int* counts = ws + WS_COUNTS;
    int* offs   = ws + WS_OFFS;
    int* cursor = ws + WS_CURSOR;
    int* bsums  = ws + WS_BSUMS;
    int* boffs  = ws + WS_BOFFS;
    unsigned long long* csr = (unsigned long long*)(ws + WS_CSR);

    // counts must start at zero (ws is poisoned before every call).
    hipMemsetAsync(counts, 0, sizeof(int) * NNODES, stream);

    hist_kernel<<<(NEDGES + 255) / 256, 256, 0, stream>>>(dst, counts);
    scan_a_kernel<<<NBLK, 256, 0, stream>>>(counts, offs, bsums);
    scan_b_kernel<<<1, 128, 0, stream>>>(bsums, boffs);
    scan_c_kernel<<<(NNODES + 255) / 256, 256, 0, stream>>>(offs, boffs, cursor);
    fill_kernel<<<(NEDGES + 255) / 256, 256, 0, stream>>>(src, dst, w, deg, lam, cursor, csr);

    const int node_threads = NNODES * QPN;  // 1.2M
    gather_kernel<<<(node_threads + 255) / 256, 256, 0, stream>>>(
        Y, X, deg, alp, lam, offs, counts, csr, out);
}

// Round 3
// 211.666 us; speedup vs baseline: 5.1272x; 1.4825x over previous
//
#include <hip/hip_runtime.h>

typedef unsigned long long u64;

// Problem constants (fixed by the reference harness).
#define NNODES 100000
#define NEDGES 1600000
#define DIM    48
#define QPN    12                 // DIM/4 float4 chunks per node

#define NBUCK  256
#define NODES_PER_BUCKET 391      // ceil(100000/256)
#define BUCKET_CAP 8192           // mean 6250, sd ~79 -> +24 sigma headroom
#define P1_EDGES_PER_WG 4096
#define P1_NWG ((NEDGES + P1_EDGES_PER_WG - 1) / P1_EDGES_PER_WG)  // 391

// Workspace layout (int granularity unless noted):
//   gcnt   [256]          @ 0        bucket edge counts
//   cbase  [256]          @ 256      bucket csr base (exclusive scan)
//   offs   [N]            @ 512      per-node csr start (global)
//   counts [N]            @ 512+N    per-node degree
//   buckets[256*CAP] u64  @ byte 802048   (16.78 MB, 8B aligned)
//   csr    [E] u64        @ byte 17579264 (12.8 MB)
#define WS_GCNT   0
#define WS_CBASE  256
#define WS_OFFS   512
#define WS_COUNTS (512 + NNODES)
#define WS_BUCKETS_BYTES 802048
#define WS_CSR_BYTES     (802048 + (size_t)NBUCK * BUCKET_CAP * 8)

// ---------------------------------------------------------------------------
// pass1: bucket edges by dst range. LDS-aggregated reservation keeps global
// atomics at ~256/WG; payload stores form 256 near-sequential streams so L2
// merges them into full-line writebacks (vs 8x amplification of random 8B).
// Payload: scale(32) | src(17) | dst_local(9).
// ---------------------------------------------------------------------------
__global__ void __launch_bounds__(256) pass1_bucket(
        const int* __restrict__ src, const int* __restrict__ dst,
        const float* __restrict__ w, const float* __restrict__ deg,
        const float* __restrict__ lam_p,
        int* __restrict__ gcnt, u64* __restrict__ buckets) {
    __shared__ int lcnt[NBUCK];
    __shared__ int lbase[NBUCK];
    const int t = threadIdx.x;
    const int e0 = blockIdx.x * P1_EDGES_PER_WG;

    lcnt[t] = 0;
    __syncthreads();

    // Phase A: local histogram of bucket ids.
    for (int i = t; i < P1_EDGES_PER_WG; i += 256) {
        const int e = e0 + i;
        if (e < NEDGES) atomicAdd(&lcnt[dst[e] / NODES_PER_BUCKET], 1);
    }
    __syncthreads();

    // Reserve contiguous ranges in each bucket.
    lbase[t] = lcnt[t] ? atomicAdd(&gcnt[t], lcnt[t]) : 0;
    lcnt[t] = 0;   // reuse as cursor
    __syncthreads();

    // Phase B: compute payload and scatter into reserved ranges.
    const float lam = *lam_p;
    for (int i = t; i < P1_EDGES_PER_WG; i += 256) {
        const int e = e0 + i;
        if (e >= NEDGES) continue;
        const int s = src[e];
        const int d = dst[e];
        const int b = d / NODES_PER_BUCKET;
        const int dl = d - b * NODES_PER_BUCKET;
        const float sc = w[e] * rsqrtf(lam * deg[s] + (1.0f - lam));
        const int slot = atomicAdd(&lcnt[b], 1);
        const u64 payload = ((u64)__float_as_uint(sc) << 32) |
                            ((u64)(unsigned)s << 9) | (unsigned)dl;
        buckets[(size_t)b * BUCKET_CAP + lbase[b] + slot] = payload;
    }
}

// ---------------------------------------------------------------------------
// Exclusive scan of 256 bucket counts -> csr bucket bases.
// ---------------------------------------------------------------------------
__global__ void scan_buckets(const int* __restrict__ gcnt, int* __restrict__ cbase) {
    const int t = threadIdx.x;
    __shared__ int sh[NBUCK];
    const int v = gcnt[t];
    sh[t] = v;
    __syncthreads();
    for (int off = 1; off < NBUCK; off <<= 1) {
        const int a = (t >= off) ? sh[t - off] : 0;
        __syncthreads();
        sh[t] += a;
        __syncthreads();
    }
    cbase[t] = sh[t] - v;
}

// ---------------------------------------------------------------------------
// pass2: per-bucket counting sort in LDS. One 512-thread WG per bucket.
// Emits offs[n], counts[n], and csr rows (contiguous ~50KB region per WG,
// so the scattered stores merge in L2).
// ---------------------------------------------------------------------------
__global__ void __launch_bounds__(512) pass2_sort(
        const u64* __restrict__ buckets, const int* __restrict__ gcnt,
        const int* __restrict__ cbase,
        int* __restrict__ offs, int* __restrict__ counts, u64* __restrict__ csr) {
    const int b = blockIdx.x;
    const int t = threadIdx.x;
    const int bcnt = gcnt[b];
    const int base = cbase[b];
    const int node0 = b * NODES_PER_BUCKET;
    const u64* bp = buckets + (size_t)b * BUCKET_CAP;

    __shared__ int hist[512];
    __shared__ int scan[512];
    __shared__ int cur[512];

    hist[t] = 0;
    __syncthreads();

    for (int i = t; i < bcnt; i += 512)
        atomicAdd(&hist[(int)(bp[i] & 511u)], 1);
    __syncthreads();

    // Inclusive Hillis-Steele scan over 512.
    scan[t] = hist[t];
    __syncthreads();
    for (int off = 1; off < 512; off <<= 1) {
        const int v = scan[t];
        const int a = (t >= off) ? scan[t - off] : 0;
        __syncthreads();
        scan[t] = v + a;
        __syncthreads();
    }
    const int excl = scan[t] - hist[t];
    cur[t] = excl;
    const int n = node0 + t;
    if (t < NODES_PER_BUCKET && n < NNODES) {
        offs[n] = base + excl;
        counts[n] = hist[t];
    }
    __syncthreads();

    for (int i = t; i < bcnt; i += 512) {
        const u64 p = bp[i];
        const int dl = (int)(p & 511u);
        const unsigned s = (unsigned)(p >> 9) & 0x1ffffu;
        const int slot = atomicAdd(&cur[dl], 1);
        csr[base + slot] = (p & 0xffffffff00000000ull) | s;
    }
}

// ---------------------------------------------------------------------------
// Gather + fused finalize. 12 threads per node, one float4 each.
// ---------------------------------------------------------------------------
__global__ void gather_kernel(const float* __restrict__ Y,
                              const float* __restrict__ X,
                              const float* __restrict__ deg,
                              const float* __restrict__ alp_p,
                              const float* __restrict__ lam_p,
                              const int* __restrict__ offs,
                              const int* __restrict__ counts,
                              const u64* __restrict__ csr,
                              float* __restrict__ out) {
    const int gid = blockIdx.x * blockDim.x + threadIdx.x;
    if (gid >= NNODES * QPN) return;
    const int n = gid / QPN;
    const int q = gid % QPN;

    const int st = offs[n];
    const int len = counts[n];

    float4 acc = make_float4(0.f, 0.f, 0.f, 0.f);
    for (int j = 0; j < len; ++j) {
        const u64 p = csr[st + j];
        const int s = (int)(unsigned)(p & 0xffffffffull);
        const float sc = __uint_as_float((unsigned)(p >> 32));
        const float4 v = ((const float4*)(Y + (size_t)s * DIM))[q];
        acc.x += v.x * sc;
        acc.y += v.y * sc;
        acc.z += v.z * sc;
        acc.w += v.w * sc;
    }

    const float alp = *alp_p;
    const float lam = *lam_p;
    const float ns = rsqrtf(lam * deg[n] + (1.0f - lam));  // norm^-0.5
    const float ni = ns * ns;                              // norm^-1
    const float c0 = 1.0f - alp;
    const float c1 = alp * lam * ns;
    const float c2 = alp * ni;

    const float4 y = ((const float4*)Y)[gid];
    const float4 x = ((const float4*)X)[gid];
    float4 r;
    r.x = c0 * y.x + c1 * acc.x + c2 * x.x;
    r.y = c0 * y.y + c1 * acc.y + c2 * x.y;
    r.z = c0 * y.z + c1 * acc.z + c2 * x.z;
    r.w = c0 * y.w + c1 * acc.w + c2 * x.w;
    ((float4*)out)[gid] = r;
}

extern "C" void kernel_launch(void* const* d_in, const int* in_sizes, int n_in,
                              void* d_out, int out_size, void* d_ws, size_t ws_size,
                              hipStream_t stream) {
    const float* Y   = (const float*)d_in[0];
    const float* X   = (const float*)d_in[1];
    const float* w   = (const float*)d_in[2];
    const float* deg = (const float*)d_in[3];
    const float* alp = (const float*)d_in[4];
    const float* lam = (const float*)d_in[5];
    const int*   src = (const int*)d_in[6];
    const int*   dst = (const int*)d_in[7];
    float* out = (float*)d_out;

    int* ws = (int*)d_ws;
    int* gcnt   = ws + WS_GCNT;
    int* cbase  = ws + WS_CBASE;
    int* offs   = ws + WS_OFFS;
    int* counts = ws + WS_COUNTS;
    u64* buckets = (u64*)((char*)d_ws + WS_BUCKETS_BYTES);
    u64* csr     = (u64*)((char*)d_ws + WS_CSR_BYTES);

    hipMemsetAsync(gcnt, 0, sizeof(int) * NBUCK, stream);

    pass1_bucket<<<P1_NWG, 256, 0, stream>>>(src, dst, w, deg, lam, gcnt, buckets);
    scan_buckets<<<1, NBUCK, 0, stream>>>(gcnt, cbase);
    pass2_sort<<<NBUCK, 512, 0, stream>>>(buckets, gcnt, cbase, offs, counts, csr);

    const int node_threads = NNODES * QPN;  // 1.2M
    gather_kernel<<<(node_threads + 255) / 256, 256, 0, stream>>>(
        Y, X, deg, alp, lam, offs, counts, csr, out);
}